// Round 15
// baseline (511.788 us; speedup 1.0000x reference)
//
#include <hip/hip_runtime.h>
#include <stdint.h>
#include <stddef.h>

typedef __bf16 bf16;
typedef bf16 bf16x8 __attribute__((ext_vector_type(8)));
typedef bf16 bf16x4 __attribute__((ext_vector_type(4)));
typedef float f32x4 __attribute__((ext_vector_type(4)));
typedef float f32x16 __attribute__((ext_vector_type(16)));

#define B_   16
#define CI   192
#define CO   192
#define H_   128
#define W_   128
#define KE   8
#define LD   64
#define KTOT 1728   // 9*192
#define HP   130    // padded H/W
#define HPHP (HP*HP)
#define NPX  (H_*W_)
#define NT   54     // K micro-steps of 32 (order: r-major, ib, s-minor)

__device__ __forceinline__ void gll16(const void* g, void* l) {
  __builtin_amdgcn_global_load_lds(
      (const __attribute__((address_space(1))) unsigned int*)g,
      (__attribute__((address_space(3))) unsigned int*)l, 16, 0, 0);
}

__device__ __forceinline__ float silu_f(float x) {
  return x / (1.f + __expf(-x));
}

// compute attn[b][k] (softmax over k of latent@attn_w^T + attn_b) into LDS, threads 0..127
__device__ __forceinline__ void attn_inline(const float* __restrict__ latent,
                                            const float* __restrict__ attn_w,
                                            const float* __restrict__ attn_b,
                                            float (*al)[KE], int tid) {
  if (tid < 128) {
    int b = tid >> 3, k = tid & 7;
    float s = attn_b[k];
    #pragma unroll 8
    for (int d = 0; d < LD; ++d) s += latent[b*LD + d] * attn_w[k*LD + d];
    float m = s;
    for (int off = 4; off; off >>= 1) m = fmaxf(m, __shfl_xor(m, off, 8));
    float e = __expf(s - m);
    float sum = e;
    for (int off = 4; off; off >>= 1) sum += __shfl_xor(sum, off, 8);
    al[b][k] = e / sum;
  }
  __syncthreads();
}

// ---------------- dynamic bias (attn inlined) ----------------
__global__ void k_bdyn(const float* __restrict__ latent, const float* __restrict__ attn_w,
                       const float* __restrict__ attn_b, const float* __restrict__ expert_b,
                       float* __restrict__ bdyn) {
  __shared__ float al[B_][KE];
  attn_inline(latent, attn_w, attn_b, al, threadIdx.x);
  int j = blockIdx.x * 256 + threadIdx.x;
  if (j >= B_ * CO) return;
  int b = j / CO, o = j - b * CO;
  float s = 0.f;
  #pragma unroll
  for (int e = 0; e < KE; ++e) s += al[b][e] * expert_b[e*CO + o];
  bdyn[j] = s;
}

// ---------------- dynamic weights -> staged layout [b][kt=54][chunk=12][slot=64][8] bf16
// K order: kt = r*18 + ib*3 + s  (s innermost). slot L holds (row=L>>2, ks=(L&3)^((row>>1)&3)).
// element: o = chunk*16+row, i = ib*32 + ks*8 + j, weight (o, i, r, s). attn inlined.
__global__ void k_wdyn(const float* __restrict__ expert_w, const float* __restrict__ latent,
                       const float* __restrict__ attn_w, const float* __restrict__ attn_b,
                       bf16* __restrict__ w_re) {
  int o = blockIdx.x;            // 192
  int chunk = o >> 4, row = o & 15, c = (row >> 1) & 3;
  __shared__ float ew[KE][KTOT];
  __shared__ float al[B_][KE];
  attn_inline(latent, attn_w, attn_b, al, threadIdx.x);
  for (int e = 0; e < KE; ++e)
    for (int j = threadIdx.x; j < KTOT; j += 256)
      ew[e][j] = expert_w[((size_t)e*CO + o)*KTOT + j];   // [i*9+rs]
  __syncthreads();
  for (int idx = threadIdx.x; idx < B_*KTOT; idx += 256) {
    int b = idx / KTOT, k = idx - b*KTOT;
    int kt = k >> 5, ks = (k >> 3) & 3, j = k & 7;
    int r = kt / 18, t2 = kt - r*18;
    int ibb = t2 / 3, s = t2 - ibb*3;
    int i = ibb*32 + ks*8 + j;
    float acc = 0.f;
    #pragma unroll
    for (int e = 0; e < KE; ++e) acc += al[b][e] * ew[e][i*9 + r*3 + s];
    int slot = row*4 + (ks ^ c);
    w_re[((((size_t)b*NT + kt)*12 + chunk)*64 + slot)*8 + j] = (bf16)acc;
  }
}

// ---------------- static conv2 weights -> same staged layout (no b) ----------------
__global__ void k_w2re(const float* __restrict__ conv2_w, bf16* __restrict__ w2_re) {
  int o = blockIdx.x;
  int chunk = o >> 4, row = o & 15, c = (row >> 1) & 3;
  __shared__ float cw[KTOT];
  for (int j = threadIdx.x; j < KTOT; j += 256) cw[j] = conv2_w[(size_t)o*KTOT + j];
  __syncthreads();
  for (int k = threadIdx.x; k < KTOT; k += 256) {
    int kt = k >> 5, ks = (k >> 3) & 3, j = k & 7;
    int r = kt / 18, t2 = kt - r*18;
    int ibb = t2 / 3, s = t2 - ibb*3;
    int i = ibb*32 + ks*8 + j;
    int slot = row*4 + (ks ^ c);
    w2_re[(((size_t)kt*12 + chunk)*64 + slot)*8 + j] = (bf16)cw[i*9 + r*3 + s];
  }
}

// ---------------- pack+pad x -> xpack bf16 [b][i/8][130][130][8]; also zero midpack borders ----
__global__ void k_xpack(const float* __restrict__ x, bf16* __restrict__ xpack,
                        bf16* __restrict__ midpack) {
  int h2 = blockIdx.x, ib = blockIdx.y, b = blockIdx.z;
  size_t rowbase = (((size_t)b*24 + ib)*HP + h2)*HP;
  int t = threadIdx.x;  // 128
  uint4 z = make_uint4(0,0,0,0);
  if (h2 == 0 || h2 == HP-1) {
    for (int w = t; w < HP; w += 128) {
      *(uint4*)(xpack   + (rowbase + w)*8) = z;
      *(uint4*)(midpack + (rowbase + w)*8) = z;
    }
    return;
  }
  __shared__ float tt[8][128];
  int h = h2 - 1;
  #pragma unroll
  for (int ii = 0; ii < 8; ++ii)
    tt[ii][t] = x[(((size_t)b*CI + ib*8 + ii)*H_ + h)*W_ + t];
  __syncthreads();
  bf16x8 v;
  #pragma unroll
  for (int ii = 0; ii < 8; ++ii) v[ii] = (bf16)tt[ii][t];
  *(bf16x8*)(xpack + (rowbase + t + 1)*8) = v;
  if (t == 0) {
    *(uint4*)(xpack + rowbase*8) = z;
    *(uint4*)(xpack + (rowbase + HP-1)*8) = z;
    *(uint4*)(midpack + rowbase*8) = z;
    *(uint4*)(midpack + (rowbase + HP-1)*8) = z;
  }
}

// ---------------- implicit-GEMM 3x3 conv, BM=192 x BN=128(1 row), K order (r,ib,s) ----------------
// R13/R14 pipeline at 3-blocks/CU geometry: LDS 54.3 KB (A 3-buf 36.9K + B 2-buf 16.6K + bias)
// -> 3 barrier domains/CU, 3 waves/SIMD (was 2). 4 waves (2m x 2n-col), per-wave 96x64 =
// 3 mt x 2 nt tiles of 32x32. B per macro = 4 kg x 1 row x 130 cols (3 overlapped gll16/kg,
// one kg per wave). Counted-vmcnt schedule re-derived for B:3 loads:
//   s0/s1 entry vmcnt(3); s2 entry vmcnt(6) (keeps A(u+1):3 + B(m+1):3); tail vmcnt(0).
// Prologue FIFO [B0:3][A0:3][A1:3] (race-fixed). Per micro: entry wait + BAR;
//   P1: kh=0 reads (3 af + 2 bv) ; stageA(u+2) ; BAR ; prio1 6 MFMA prio0
//   P2: kh=1 reads (3 af + 2 bv) ; stageB(m+1)@s1 ; BAR ; prio1 6 MFMA prio0
// A frag (mt,kh): chunk = wm*6+mt*2+((l>>4)&1), row16 = l&15, kslot = kh*2+(l>>5), baked XOR.
// B frag (nt,kh): kg = kh*2+(l>>5), col = wn*64+nt*32+(l&31) (+s shift).
// C/D: col = l&31, row = (reg&3)+8*(reg>>2)+4*(l>>5).
template<int MODE>
__global__ __launch_bounds__(256, 2)
void k_conv(const bf16* __restrict__ wre, const bf16* __restrict__ inpack,
            const float* __restrict__ bias_g, const bf16* __restrict__ respack,
            bf16* __restrict__ outpack, float* __restrict__ outp) {
  const int tid  = threadIdx.x;
  const int lane = tid & 63;
  const int wv   = tid >> 6;          // 0..3
  const int wm   = wv >> 1;           // 0..1 (o half)
  const int wn   = wv & 1;            // 0..1 (column half of 128)
  const int l15  = lane & 15;
  const int l31  = lane & 31;
  const int lhi  = lane >> 5;         // 0..1

  // XCD-aware chunked remap: 2048 blocks, 256/XCD => each XCD owns 2 batches
  const int bid  = blockIdx.x;
  const int n    = (bid & 7) * 256 + (bid >> 3);
  const int b    = n >> 7;
  const int row  = n & 127;           // output image row

  __shared__ __align__(16) bf16 Alds[3][12*512];    // 36864 B
  __shared__ __align__(16) bf16 Blds[2][4*1040];    // 16640 B
  __shared__ float bias_lds[CO];                    // 768 B  -> total 54272 B, 3 blocks/CU

  if (tid < CO) bias_lds[tid] = (MODE == 0) ? bias_g[b*CO + tid] : bias_g[tid];

  const size_t wbase = (MODE == 0) ? ((size_t)b*CO*KTOT) : 0;

  // A staging: 12 chunks of 1KB per micro-step; wave wv stages {wv, wv+4, wv+8}
  const bf16* aS = wre + wbase + (size_t)wv*512 + lane*8;
  // B staging: wave wv stages kg=wv (channel group ib*4+wv); 3 overlapped 1KB chunks per row
  const bf16* bbase = inpack + (((size_t)b*24 + wv)*HPHP + (size_t)row*HP)*8 + lane*8;
  int ibm = 0; ptrdiff_t boffEl = 0;   // macro (r,ib) element offset

  auto stageA = [&](bf16* dbuf) {
    bf16* d = dbuf + wv*512;
    gll16(aS,        d);
    gll16(aS + 2048, d + 2048);
    gll16(aS + 4096, d + 4096);
    aS += 6144;
  };
  auto stageB = [&](bf16* dbuf) {
    const bf16* src = bbase + boffEl;
    bf16* d = dbuf + wv*1040;
    gll16(src,       d);
    gll16(src + 512, d + 512);
    gll16(src + 528, d + 528);   // overlapped tail chunk (el 528..1039)
    if (++ibm == 6) { ibm = 0; boffEl += (ptrdiff_t)(HP - 20*HPHP)*8; }
    else boffEl += (ptrdiff_t)4*HPHP*8;
  };

  f32x16 acc[3][2];
  #pragma unroll
  for (int mt = 0; mt < 3; ++mt)
    #pragma unroll
    for (int nt = 0; nt < 2; ++nt)
      #pragma unroll
      for (int jj = 0; jj < 16; ++jj) acc[mt][nt][jj] = 0.f;

  // A-read constants: element offset within chunk for (row16, kslot) with baked slot-XOR
  const int arow   = l15;
  const int aswz   = (arow >> 1) & 3;
  const int achnk  = (lane >> 4) & 1;                 // +0/+1 chunk for rows 16-31
  const int aoff0  = arow*32 + ((lhi       ^ aswz) * 8);   // kh=0: kslot = 0..1
  const int aoff1  = arow*32 + (((2 + lhi) ^ aswz) * 8);   // kh=1: kslot = 2..3
  // B-read constants
  const int bcol   = (wn*64 + l31) * 8;               // column within 130-wide row
  const int bkg    = lhi * 1040;                      // kg low bit from lane>>5

  // prologue FIFO: [B(0):3][A(0):3][A(1):3] — first entry vmcnt(3) drains B0+A0, keeps A1
  stageB(Blds[0]);
  stageA(Alds[0]);
  stageA(Alds[1]);

  bf16* Bcur = (bf16*)Blds[0];
  bf16* Bnxt = (bf16*)Blds[1];

  for (int m = 0; m < 18; ++m) {
    #pragma unroll
    for (int s = 0; s < 3; ++s) {
      // ---- entry wait + barrier (counted schedule, B:3 loads) ----
      if (s == 2) {
        if (m == 17) asm volatile("s_waitcnt vmcnt(0)" ::: "memory");
        else         asm volatile("s_waitcnt vmcnt(6)" ::: "memory");
      } else {
        asm volatile("s_waitcnt vmcnt(3)" ::: "memory");
      }
      __builtin_amdgcn_s_barrier();

      const bf16* A  = Alds[s];                        // u%3 == s
      const bf16* bp = Bcur + bkg + bcol + s*8;        // kh=1 adds +2*1040

      // ---- P1: kh=0 reads ; stageA(u+2) ; 6 MFMA ----
      bf16x8 a0 = *(const bf16x8*)(A + (wm*6 + 0 + achnk)*512 + aoff0);
      bf16x8 a1 = *(const bf16x8*)(A + (wm*6 + 2 + achnk)*512 + aoff0);
      bf16x8 a2 = *(const bf16x8*)(A + (wm*6 + 4 + achnk)*512 + aoff0);
      bf16x8 b0 = *(const bf16x8*)(bp);
      bf16x8 b1 = *(const bf16x8*)(bp + 256);

      if (3*m + s + 2 < NT) stageA(Alds[(s+2)%3]);     // A(u+2)

      __builtin_amdgcn_s_barrier();
      __builtin_amdgcn_s_setprio(1);
      acc[0][0] = __builtin_amdgcn_mfma_f32_32x32x16_bf16(a0, b0, acc[0][0], 0, 0, 0);
      acc[0][1] = __builtin_amdgcn_mfma_f32_32x32x16_bf16(a0, b1, acc[0][1], 0, 0, 0);
      acc[1][0] = __builtin_amdgcn_mfma_f32_32x32x16_bf16(a1, b0, acc[1][0], 0, 0, 0);
      acc[1][1] = __builtin_amdgcn_mfma_f32_32x32x16_bf16(a1, b1, acc[1][1], 0, 0, 0);
      acc[2][0] = __builtin_amdgcn_mfma_f32_32x32x16_bf16(a2, b0, acc[2][0], 0, 0, 0);
      acc[2][1] = __builtin_amdgcn_mfma_f32_32x32x16_bf16(a2, b1, acc[2][1], 0, 0, 0);
      __builtin_amdgcn_s_setprio(0);

      // ---- P2: kh=1 reads ; stageB(m+1)@s1 ; 6 MFMA ----
      bf16x8 a3 = *(const bf16x8*)(A + (wm*6 + 0 + achnk)*512 + aoff1);
      bf16x8 a4 = *(const bf16x8*)(A + (wm*6 + 2 + achnk)*512 + aoff1);
      bf16x8 a5 = *(const bf16x8*)(A + (wm*6 + 4 + achnk)*512 + aoff1);
      bf16x8 b2 = *(const bf16x8*)(bp + 2*1040);
      bf16x8 b3 = *(const bf16x8*)(bp + 2*1040 + 256);

      if (s == 1 && m < 17) stageB(Bnxt);              // B(m+1)

      __builtin_amdgcn_s_barrier();
      __builtin_amdgcn_s_setprio(1);
      acc[0][0] = __builtin_amdgcn_mfma_f32_32x32x16_bf16(a3, b2, acc[0][0], 0, 0, 0);
      acc[0][1] = __builtin_amdgcn_mfma_f32_32x32x16_bf16(a3, b3, acc[0][1], 0, 0, 0);
      acc[1][0] = __builtin_amdgcn_mfma_f32_32x32x16_bf16(a4, b2, acc[1][0], 0, 0, 0);
      acc[1][1] = __builtin_amdgcn_mfma_f32_32x32x16_bf16(a4, b3, acc[1][1], 0, 0, 0);
      acc[2][0] = __builtin_amdgcn_mfma_f32_32x32x16_bf16(a5, b2, acc[2][0], 0, 0, 0);
      acc[2][1] = __builtin_amdgcn_mfma_f32_32x32x16_bf16(a5, b3, acc[2][1], 0, 0, 0);
      __builtin_amdgcn_s_setprio(0);
    }
    { bf16* t = Bcur; Bcur = Bnxt; Bnxt = t; }
  }

  // epilogue: C/D 32x32 mapping: col=l31, row=(reg&3)+8*(reg>>2)+4*lhi
  #pragma unroll
  for (int mt = 0; mt < 3; ++mt) {
    #pragma unroll
    for (int nt = 0; nt < 2; ++nt) {
      int w = wn*64 + nt*32 + l31;
      int p = row*128 + w;
      #pragma unroll
      for (int rq = 0; rq < 4; ++rq) {
        int ob = wm*96 + mt*32 + rq*8 + 4*lhi;     // 4 consecutive channels
        size_t basep = (((size_t)b*24 + (ob >> 3))*HP + (row + 1))*HP + (w + 1);
        if (MODE == 0) {
          bf16x4 pk;
          #pragma unroll
          for (int jj = 0; jj < 4; ++jj) {
            float xv = acc[mt][nt][rq*4 + jj] + bias_lds[ob + jj];
            pk[jj] = (bf16)silu_f(xv);
          }
          *(bf16x4*)(outpack + basep*8 + (ob & 7)) = pk;
        } else {
          bf16x4 rr = *(const bf16x4*)(respack + basep*8 + (ob & 7));
          #pragma unroll
          for (int jj = 0; jj < 4; ++jj) {
            float xv = silu_f(acc[mt][nt][rq*4 + jj] + bias_lds[ob + jj]);
            size_t idx = ((size_t)b*CO + ob + jj)*NPX + p;
            outp[idx] = xv + (float)rr[jj];
          }
        }
      }
    }
  }
}

extern "C" void kernel_launch(void* const* d_in, const int* in_sizes, int n_in,
                              void* d_out, int out_size, void* d_ws, size_t ws_size,
                              hipStream_t stream) {
  const float* x        = (const float*)d_in[0];
  const float* latent   = (const float*)d_in[1];
  const float* expert_w = (const float*)d_in[2];
  const float* expert_b = (const float*)d_in[3];
  const float* attn_w   = (const float*)d_in[4];
  const float* attn_b   = (const float*)d_in[5];
  const float* conv2_w  = (const float*)d_in[6];
  const float* conv2_b  = (const float*)d_in[7];
  float* outp = (float*)d_out;

  char* base = (char*)d_ws;
  size_t off = 0;
  float* bdyn = (float*)(base + off); off += 16384;
  bf16* w_re  = (bf16*)(base + off);  off += (size_t)B_*CO*KTOT*2;      // 10.6 MB
  bf16* w2_re = (bf16*)(base + off);  off += (size_t)CO*KTOT*2;         // 0.66 MB
  bf16* xpack = (bf16*)(base + off);  off += (size_t)B_*24*HPHP*8*2;    // 103.8 MB
  bf16* midpack = (bf16*)(base + off); off += (size_t)B_*24*HPHP*8*2;   // 103.8 MB
  (void)ws_size; (void)in_sizes; (void)n_in; (void)out_size;

  k_xpack<<<dim3(130, 24, 16), dim3(128), 0, stream>>>(x, xpack, midpack);
  k_wdyn<<<dim3(CO), dim3(256), 0, stream>>>(expert_w, latent, attn_w, attn_b, w_re);
  k_bdyn<<<dim3(12), dim3(256), 0, stream>>>(latent, attn_w, attn_b, expert_b, bdyn);
  k_w2re<<<dim3(CO), dim3(256), 0, stream>>>(conv2_w, w2_re);
  k_conv<0><<<dim3(2048), dim3(256), 0, stream>>>(w_re, xpack, bdyn, xpack, midpack, outp);
  k_conv<1><<<dim3(2048), dim3(256), 0, stream>>>(w2_re, midpack, conv2_b, xpack, midpack, outp);
}

// Round 16
// 460.110 us; speedup vs baseline: 1.1123x; 1.1123x over previous
//
#include <hip/hip_runtime.h>
#include <stdint.h>
#include <stddef.h>

typedef __bf16 bf16;
typedef bf16 bf16x8 __attribute__((ext_vector_type(8)));
typedef bf16 bf16x4 __attribute__((ext_vector_type(4)));
typedef float f32x4 __attribute__((ext_vector_type(4)));
typedef float f32x16 __attribute__((ext_vector_type(16)));

#define B_   16
#define CI   192
#define CO   192
#define H_   128
#define W_   128
#define KE   8
#define LD   64
#define KTOT 1728   // 9*192
#define HP   130    // padded H/W
#define HPHP (HP*HP)
#define NPX  (H_*W_)
#define NT   54     // K micro-steps of 32 (order: r-major, ib, s-minor)

__device__ __forceinline__ void gll16(const void* g, void* l) {
  __builtin_amdgcn_global_load_lds(
      (const __attribute__((address_space(1))) unsigned int*)g,
      (__attribute__((address_space(3))) unsigned int*)l, 16, 0, 0);
}

__device__ __forceinline__ float silu_f(float x) {
  return x / (1.f + __expf(-x));
}

// compute attn[b][k] (softmax over k of latent@attn_w^T + attn_b) into LDS, threads 0..127
__device__ __forceinline__ void attn_inline(const float* __restrict__ latent,
                                            const float* __restrict__ attn_w,
                                            const float* __restrict__ attn_b,
                                            float (*al)[KE], int tid) {
  if (tid < 128) {
    int b = tid >> 3, k = tid & 7;
    float s = attn_b[k];
    #pragma unroll 8
    for (int d = 0; d < LD; ++d) s += latent[b*LD + d] * attn_w[k*LD + d];
    float m = s;
    for (int off = 4; off; off >>= 1) m = fmaxf(m, __shfl_xor(m, off, 8));
    float e = __expf(s - m);
    float sum = e;
    for (int off = 4; off; off >>= 1) sum += __shfl_xor(sum, off, 8);
    al[b][k] = e / sum;
  }
  __syncthreads();
}

// ---------------- dynamic bias (attn inlined) ----------------
__global__ void k_bdyn(const float* __restrict__ latent, const float* __restrict__ attn_w,
                       const float* __restrict__ attn_b, const float* __restrict__ expert_b,
                       float* __restrict__ bdyn) {
  __shared__ float al[B_][KE];
  attn_inline(latent, attn_w, attn_b, al, threadIdx.x);
  int j = blockIdx.x * 256 + threadIdx.x;
  if (j >= B_ * CO) return;
  int b = j / CO, o = j - b * CO;
  float s = 0.f;
  #pragma unroll
  for (int e = 0; e < KE; ++e) s += al[b][e] * expert_b[e*CO + o];
  bdyn[j] = s;
}

// ---------------- dynamic weights -> staged layout [b][kt=54][chunk=12][slot=64][8] bf16
// K order: kt = r*18 + ib*3 + s  (s innermost). slot L holds (row=L>>2, ks=(L&3)^((row>>1)&3)).
// element: o = chunk*16+row, i = ib*32 + ks*8 + j, weight (o, i, r, s). attn inlined.
__global__ void k_wdyn(const float* __restrict__ expert_w, const float* __restrict__ latent,
                       const float* __restrict__ attn_w, const float* __restrict__ attn_b,
                       bf16* __restrict__ w_re) {
  int o = blockIdx.x;            // 192
  int chunk = o >> 4, row = o & 15, c = (row >> 1) & 3;
  __shared__ float ew[KE][KTOT];
  __shared__ float al[B_][KE];
  attn_inline(latent, attn_w, attn_b, al, threadIdx.x);
  for (int e = 0; e < KE; ++e)
    for (int j = threadIdx.x; j < KTOT; j += 256)
      ew[e][j] = expert_w[((size_t)e*CO + o)*KTOT + j];   // [i*9+rs]
  __syncthreads();
  for (int idx = threadIdx.x; idx < B_*KTOT; idx += 256) {
    int b = idx / KTOT, k = idx - b*KTOT;
    int kt = k >> 5, ks = (k >> 3) & 3, j = k & 7;
    int r = kt / 18, t2 = kt - r*18;
    int ibb = t2 / 3, s = t2 - ibb*3;
    int i = ibb*32 + ks*8 + j;
    float acc = 0.f;
    #pragma unroll
    for (int e = 0; e < KE; ++e) acc += al[b][e] * ew[e][i*9 + r*3 + s];
    int slot = row*4 + (ks ^ c);
    w_re[((((size_t)b*NT + kt)*12 + chunk)*64 + slot)*8 + j] = (bf16)acc;
  }
}

// ---------------- static conv2 weights -> same staged layout (no b) ----------------
__global__ void k_w2re(const float* __restrict__ conv2_w, bf16* __restrict__ w2_re) {
  int o = blockIdx.x;
  int chunk = o >> 4, row = o & 15, c = (row >> 1) & 3;
  __shared__ float cw[KTOT];
  for (int j = threadIdx.x; j < KTOT; j += 256) cw[j] = conv2_w[(size_t)o*KTOT + j];
  __syncthreads();
  for (int k = threadIdx.x; k < KTOT; k += 256) {
    int kt = k >> 5, ks = (k >> 3) & 3, j = k & 7;
    int r = kt / 18, t2 = kt - r*18;
    int ibb = t2 / 3, s = t2 - ibb*3;
    int i = ibb*32 + ks*8 + j;
    int slot = row*4 + (ks ^ c);
    w2_re[(((size_t)kt*12 + chunk)*64 + slot)*8 + j] = (bf16)cw[i*9 + r*3 + s];
  }
}

// ---------------- pack+pad x -> xpack bf16 [b][i/8][130][130][8]; also zero midpack borders ----
__global__ void k_xpack(const float* __restrict__ x, bf16* __restrict__ xpack,
                        bf16* __restrict__ midpack) {
  int h2 = blockIdx.x, ib = blockIdx.y, b = blockIdx.z;
  size_t rowbase = (((size_t)b*24 + ib)*HP + h2)*HP;
  int t = threadIdx.x;  // 128
  uint4 z = make_uint4(0,0,0,0);
  if (h2 == 0 || h2 == HP-1) {
    for (int w = t; w < HP; w += 128) {
      *(uint4*)(xpack   + (rowbase + w)*8) = z;
      *(uint4*)(midpack + (rowbase + w)*8) = z;
    }
    return;
  }
  __shared__ float tt[8][128];
  int h = h2 - 1;
  #pragma unroll
  for (int ii = 0; ii < 8; ++ii)
    tt[ii][t] = x[(((size_t)b*CI + ib*8 + ii)*H_ + h)*W_ + t];
  __syncthreads();
  bf16x8 v;
  #pragma unroll
  for (int ii = 0; ii < 8; ++ii) v[ii] = (bf16)tt[ii][t];
  *(bf16x8*)(xpack + (rowbase + t + 1)*8) = v;
  if (t == 0) {
    *(uint4*)(xpack + rowbase*8) = z;
    *(uint4*)(xpack + (rowbase + HP-1)*8) = z;
    *(uint4*)(midpack + rowbase*8) = z;
    *(uint4*)(midpack + (rowbase + HP-1)*8) = z;
  }
}

// ---------------- implicit-GEMM 3x3 conv, BM=192 x BN=256(2 rows), K order (r,ib,s) ----------------
// Session-optimal kernel (verified 199us/conv, absmax 0.031):
// race-fixed prologue [B0,A0,A1], counted-vmcnt, 2-phase micro, T5 setprio, 32x32x16 MFMA.
// 4 waves (2m x 2n), per-wave 96x128 = 3 mt x 4 nt tiles of 32x32.
// A frag (mt,kh): chunk = wm*6+mt*2+((l>>4)&1), row16 = l&15, kslot = kh*2+(l>>5),
//   baked slot-XOR -> row = lane&31, k = kslot*8+j. B frag (nt,kh): kg = kh*2+(l>>5),
//   col = nt*32+(l&31) (+s col shift). C/D: col = l&31, row = (reg&3)+8*(reg>>2)+4*(l>>5).
// Per micro: entry vmcnt(3)/(3)/(8|0) + BAR;
//   P1: kh=0 reads (3 af + 4 bv) ; stageA(u+2) ; BAR ; prio1 12 MFMA prio0
//   P2: kh=1 reads (3 af + 4 bv) ; stageB(m+1)@s1 ; BAR ; prio1 12 MFMA prio0
template<int MODE>
__global__ __launch_bounds__(256, 2)
void k_conv(const bf16* __restrict__ wre, const bf16* __restrict__ inpack,
            const float* __restrict__ bias_g, const bf16* __restrict__ respack,
            bf16* __restrict__ outpack, float* __restrict__ outp) {
  const int tid  = threadIdx.x;
  const int lane = tid & 63;
  const int wv   = tid >> 6;          // 0..3
  const int wm   = wv >> 1;           // 0..1 (o half)
  const int wn   = wv & 1;            // 0..1 (p half = image row)
  const int l15  = lane & 15;
  const int l31  = lane & 31;
  const int lhi  = lane >> 5;         // 0..1

  // XCD-aware chunked remap: 1024 blocks, 128/XCD => each XCD owns 2 batches
  const int bid  = blockIdx.x;
  const int n    = (bid & 7) * 128 + (bid >> 3);
  const int b    = n >> 6;
  const int tile = n & 63;
  const int p0   = tile * 256;
  const int h0   = tile * 2;

  __shared__ __align__(16) bf16 Alds[3][12*512];    // 36864 B
  __shared__ __align__(16) bf16 Blds[2][4*2560];    // 40960 B
  __shared__ float bias_lds[CO];

  if (tid < CO) bias_lds[tid] = (MODE == 0) ? bias_g[b*CO + tid] : bias_g[tid];

  const size_t wbase = (MODE == 0) ? ((size_t)b*CO*KTOT) : 0;

  // A staging: 12 chunks of 1KB per micro-step; wave wv stages {wv, wv+4, wv+8}
  const bf16* aS = wre + wbase + (size_t)wv*512 + lane*8;
  // B staging: wave wv stages kg=wv; 5 overlapped chunks over contiguous row-pair (4160B)
  const bf16* bbase = inpack + (((size_t)b*24 + wv)*HPHP + (size_t)h0*HP)*8 + lane*8;
  int ibm = 0; ptrdiff_t boffEl = 0;   // macro (r,ib) element offset

  auto stageA = [&](bf16* dbuf) {
    bf16* d = dbuf + wv*512;
    gll16(aS,        d);
    gll16(aS + 2048, d + 2048);
    gll16(aS + 4096, d + 4096);
    aS += 6144;
  };
  auto stageB = [&](bf16* dbuf) {
    const bf16* src = bbase + boffEl;
    bf16* d = dbuf + wv*2560;
    gll16(src,        d);
    gll16(src +  512, d +  512);
    gll16(src + 1024, d + 1024);
    gll16(src + 1536, d + 1536);
    gll16(src + 1568, d + 1568);   // overlapped tail chunk (3136..4159 B)
    if (++ibm == 6) { ibm = 0; boffEl += (ptrdiff_t)(HP - 20*HPHP)*8; }
    else boffEl += (ptrdiff_t)4*HPHP*8;
  };

  f32x16 acc[3][4];
  #pragma unroll
  for (int mt = 0; mt < 3; ++mt)
    #pragma unroll
    for (int nt = 0; nt < 4; ++nt)
      #pragma unroll
      for (int jj = 0; jj < 16; ++jj) acc[mt][nt][jj] = 0.f;

  // A-read constants: element offset within chunk for (row16, kslot) with baked slot-XOR
  const int arow   = l15;
  const int aswz   = (arow >> 1) & 3;
  const int achnk  = (lane >> 4) & 1;                 // +0/+1 chunk for rows 16-31
  const int aoff0  = arow*32 + ((lhi       ^ aswz) * 8);   // kh=0: kslot = 0..1
  const int aoff1  = arow*32 + (((2 + lhi) ^ aswz) * 8);   // kh=1: kslot = 2..3
  // B-read constants
  const int bcol   = (wn*130 + l31) * 8;              // (row=wn, col=l31) base, elements
  const int bkg    = lhi * 2560;                      // kg low bit from lane>>5

  // prologue FIFO: [B(0):5][A(0):3][A(1):3] — first entry vmcnt(3) drains B0+A0, keeps A1
  stageB(Blds[0]);
  stageA(Alds[0]);
  stageA(Alds[1]);

  bf16* Bcur = (bf16*)Blds[0];
  bf16* Bnxt = (bf16*)Blds[1];

  for (int m = 0; m < 18; ++m) {
    #pragma unroll
    for (int s = 0; s < 3; ++s) {
      // ---- entry wait + barrier (counted schedule) ----
      if (s == 2) {
        if (m == 17) asm volatile("s_waitcnt vmcnt(0)" ::: "memory");
        else         asm volatile("s_waitcnt vmcnt(8)" ::: "memory");
      } else {
        asm volatile("s_waitcnt vmcnt(3)" ::: "memory");
      }
      __builtin_amdgcn_s_barrier();

      const bf16* A  = Alds[s];                        // u%3 == s
      const bf16* bp = Bcur + bkg + bcol + s*8;        // kh=1 adds +2*2560

      // ---- P1: kh=0 reads ; stageA(u+2) ; 12 MFMA ----
      bf16x8 a0 = *(const bf16x8*)(A + (wm*6 + 0 + achnk)*512 + aoff0);
      bf16x8 a1 = *(const bf16x8*)(A + (wm*6 + 2 + achnk)*512 + aoff0);
      bf16x8 a2 = *(const bf16x8*)(A + (wm*6 + 4 + achnk)*512 + aoff0);
      bf16x8 b0 = *(const bf16x8*)(bp);
      bf16x8 b1 = *(const bf16x8*)(bp + 256);
      bf16x8 b2 = *(const bf16x8*)(bp + 512);
      bf16x8 b3 = *(const bf16x8*)(bp + 768);

      if (3*m + s + 2 < NT) stageA(Alds[(s+2)%3]);     // A(u+2)

      __builtin_amdgcn_s_barrier();
      __builtin_amdgcn_s_setprio(1);
      acc[0][0] = __builtin_amdgcn_mfma_f32_32x32x16_bf16(a0, b0, acc[0][0], 0, 0, 0);
      acc[0][1] = __builtin_amdgcn_mfma_f32_32x32x16_bf16(a0, b1, acc[0][1], 0, 0, 0);
      acc[0][2] = __builtin_amdgcn_mfma_f32_32x32x16_bf16(a0, b2, acc[0][2], 0, 0, 0);
      acc[0][3] = __builtin_amdgcn_mfma_f32_32x32x16_bf16(a0, b3, acc[0][3], 0, 0, 0);
      acc[1][0] = __builtin_amdgcn_mfma_f32_32x32x16_bf16(a1, b0, acc[1][0], 0, 0, 0);
      acc[1][1] = __builtin_amdgcn_mfma_f32_32x32x16_bf16(a1, b1, acc[1][1], 0, 0, 0);
      acc[1][2] = __builtin_amdgcn_mfma_f32_32x32x16_bf16(a1, b2, acc[1][2], 0, 0, 0);
      acc[1][3] = __builtin_amdgcn_mfma_f32_32x32x16_bf16(a1, b3, acc[1][3], 0, 0, 0);
      acc[2][0] = __builtin_amdgcn_mfma_f32_32x32x16_bf16(a2, b0, acc[2][0], 0, 0, 0);
      acc[2][1] = __builtin_amdgcn_mfma_f32_32x32x16_bf16(a2, b1, acc[2][1], 0, 0, 0);
      acc[2][2] = __builtin_amdgcn_mfma_f32_32x32x16_bf16(a2, b2, acc[2][2], 0, 0, 0);
      acc[2][3] = __builtin_amdgcn_mfma_f32_32x32x16_bf16(a2, b3, acc[2][3], 0, 0, 0);
      __builtin_amdgcn_s_setprio(0);

      // ---- P2: kh=1 reads ; stageB(m+1)@s1 ; 12 MFMA ----
      bf16x8 a3 = *(const bf16x8*)(A + (wm*6 + 0 + achnk)*512 + aoff1);
      bf16x8 a4 = *(const bf16x8*)(A + (wm*6 + 2 + achnk)*512 + aoff1);
      bf16x8 a5 = *(const bf16x8*)(A + (wm*6 + 4 + achnk)*512 + aoff1);
      bf16x8 b4 = *(const bf16x8*)(bp + 2*2560);
      bf16x8 b5 = *(const bf16x8*)(bp + 2*2560 + 256);
      bf16x8 b6 = *(const bf16x8*)(bp + 2*2560 + 512);
      bf16x8 b7 = *(const bf16x8*)(bp + 2*2560 + 768);

      if (s == 1 && m < 17) stageB(Bnxt);              // B(m+1)

      __builtin_amdgcn_s_barrier();
      __builtin_amdgcn_s_setprio(1);
      acc[0][0] = __builtin_amdgcn_mfma_f32_32x32x16_bf16(a3, b4, acc[0][0], 0, 0, 0);
      acc[0][1] = __builtin_amdgcn_mfma_f32_32x32x16_bf16(a3, b5, acc[0][1], 0, 0, 0);
      acc[0][2] = __builtin_amdgcn_mfma_f32_32x32x16_bf16(a3, b6, acc[0][2], 0, 0, 0);
      acc[0][3] = __builtin_amdgcn_mfma_f32_32x32x16_bf16(a3, b7, acc[0][3], 0, 0, 0);
      acc[1][0] = __builtin_amdgcn_mfma_f32_32x32x16_bf16(a4, b4, acc[1][0], 0, 0, 0);
      acc[1][1] = __builtin_amdgcn_mfma_f32_32x32x16_bf16(a4, b5, acc[1][1], 0, 0, 0);
      acc[1][2] = __builtin_amdgcn_mfma_f32_32x32x16_bf16(a4, b6, acc[1][2], 0, 0, 0);
      acc[1][3] = __builtin_amdgcn_mfma_f32_32x32x16_bf16(a4, b7, acc[1][3], 0, 0, 0);
      acc[2][0] = __builtin_amdgcn_mfma_f32_32x32x16_bf16(a5, b4, acc[2][0], 0, 0, 0);
      acc[2][1] = __builtin_amdgcn_mfma_f32_32x32x16_bf16(a5, b5, acc[2][1], 0, 0, 0);
      acc[2][2] = __builtin_amdgcn_mfma_f32_32x32x16_bf16(a5, b6, acc[2][2], 0, 0, 0);
      acc[2][3] = __builtin_amdgcn_mfma_f32_32x32x16_bf16(a5, b7, acc[2][3], 0, 0, 0);
      __builtin_amdgcn_s_setprio(0);
    }
    { bf16* t = Bcur; Bcur = Bnxt; Bnxt = t; }
  }

  // epilogue: C/D 32x32 mapping: col=l31, row=(reg&3)+8*(reg>>2)+4*lhi
  #pragma unroll
  for (int mt = 0; mt < 3; ++mt) {
    #pragma unroll
    for (int nt = 0; nt < 4; ++nt) {
      int w = nt*32 + l31;
      int p = p0 + wn*128 + w;
      #pragma unroll
      for (int rq = 0; rq < 4; ++rq) {
        int ob = wm*96 + mt*32 + rq*8 + 4*lhi;     // 4 consecutive channels
        size_t basep = (((size_t)b*24 + (ob >> 3))*HP + (h0 + wn + 1))*HP + (w + 1);
        if (MODE == 0) {
          bf16x4 pk;
          #pragma unroll
          for (int jj = 0; jj < 4; ++jj) {
            float xv = acc[mt][nt][rq*4 + jj] + bias_lds[ob + jj];
            pk[jj] = (bf16)silu_f(xv);
          }
          *(bf16x4*)(outpack + basep*8 + (ob & 7)) = pk;
        } else {
          bf16x4 rr = *(const bf16x4*)(respack + basep*8 + (ob & 7));
          #pragma unroll
          for (int jj = 0; jj < 4; ++jj) {
            float xv = silu_f(acc[mt][nt][rq*4 + jj] + bias_lds[ob + jj]);
            size_t idx = ((size_t)b*CO + ob + jj)*NPX + p;
            outp[idx] = xv + (float)rr[jj];
          }
        }
      }
    }
  }
}

extern "C" void kernel_launch(void* const* d_in, const int* in_sizes, int n_in,
                              void* d_out, int out_size, void* d_ws, size_t ws_size,
                              hipStream_t stream) {
  const float* x        = (const float*)d_in[0];
  const float* latent   = (const float*)d_in[1];
  const float* expert_w = (const float*)d_in[2];
  const float* expert_b = (const float*)d_in[3];
  const float* attn_w   = (const float*)d_in[4];
  const float* attn_b   = (const float*)d_in[5];
  const float* conv2_w  = (const float*)d_in[6];
  const float* conv2_b  = (const float*)d_in[7];
  float* outp = (float*)d_out;

  char* base = (char*)d_ws;
  size_t off = 0;
  float* bdyn = (float*)(base + off); off += 16384;
  bf16* w_re  = (bf16*)(base + off);  off += (size_t)B_*CO*KTOT*2;      // 10.6 MB
  bf16* w2_re = (bf16*)(base + off);  off += (size_t)CO*KTOT*2;         // 0.66 MB
  bf16* xpack = (bf16*)(base + off);  off += (size_t)B_*24*HPHP*8*2;    // 103.8 MB
  bf16* midpack = (bf16*)(base + off); off += (size_t)B_*24*HPHP*8*2;   // 103.8 MB
  (void)ws_size; (void)in_sizes; (void)n_in; (void)out_size;

  k_xpack<<<dim3(130, 24, 16), dim3(128), 0, stream>>>(x, xpack, midpack);
  k_wdyn<<<dim3(CO), dim3(256), 0, stream>>>(expert_w, latent, attn_w, attn_b, w_re);
  k_bdyn<<<dim3(12), dim3(256), 0, stream>>>(latent, attn_w, attn_b, expert_b, bdyn);
  k_w2re<<<dim3(CO), dim3(256), 0, stream>>>(conv2_w, w2_re);
  k_conv<0><<<dim3(1024), dim3(256), 0, stream>>>(w_re, xpack, bdyn, xpack, midpack, outp);
  k_conv<1><<<dim3(1024), dim3(256), 0, stream>>>(w2_re, midpack, conv2_b, xpack, midpack, outp);
}